// Round 10
// baseline (778.662 us; speedup 1.0000x reference)
//
#include <hip/hip_runtime.h>

typedef _Float16 f16;
typedef _Float16 f16x8 __attribute__((ext_vector_type(8)));
typedef float    f32x4 __attribute__((ext_vector_type(4)));
typedef unsigned int       u32;
typedef unsigned short     u16;
typedef unsigned long long u64;

#define HD    64
#define GW    8       // batches per group (tile cols 0-7; cols 8-15 garbage)
#define NT    512     // 8 waves; 2 blocks co-resident per CU (de-phased streams)
#define CHUNK 8       // steps per flag update
#define XCH   256     // x staging chunk (timesteps)
#define PSZ   2048    // ring page bytes (hi-precision only)
#define L2E   1.44269504088896340736f
#define L2E2  2.88539008177792681472f

// Barrier that waits ONLY on LDS (lgkmcnt) — in-flight global sc1 traffic
// (vmcnt) stays outstanding across it.
#define BAR_LGKM() asm volatile("s_waitcnt lgkmcnt(0)\ns_barrier" ::: "memory")

#if __has_builtin(__builtin_amdgcn_exp2f)
#define EXP2(x) __builtin_amdgcn_exp2f(x)
#else
#define EXP2(x) __expf((x) * 0.69314718055994530942f)
#endif

__device__ __forceinline__ f32x4 MFMA(f16x8 a, f16x8 b, f32x4 c) {
    return __builtin_amdgcn_mfma_f32_16x16x32_f16(a, b, c, 0, 0, 0);
}
// unit->k permutation (conflict-free packed publishes); kinv maps k -> unit
__device__ __forceinline__ int kinv(int k) {
    int kf = k >> 5, qk = (k >> 3) & 3, j = k & 7;
    int tile = (kf << 3) | (qk << 1) | (j & 1);
    return tile * 4 + (j >> 1);
}
__device__ __forceinline__ u32 packf16(f16 a, f16 b) {
    union { f16 h[2]; u32 u; } x; x.h[0] = a; x.h[1] = b; return x.u;
}
// relaxed poll, NO acquire fence: ring data read via sc1 (LLC) loads.
__device__ __forceinline__ u64 pollflag(u64* p, u64 need) {
    int guard = 0; u64 v;
    while ((v = __hip_atomic_load(p, __ATOMIC_RELAXED, __HIP_MEMORY_SCOPE_AGENT)) < need) {
        __builtin_amdgcn_s_sleep(2);
        if (++guard > (1 << 20)) break;   // fail visibly, don't hang
    }
    return v;
}

// Gate inputs pre-scaled: gi,gf,go by log2(e); gg by 2*log2(e).
// Cell state kept PRE-SCALED: cL = c * 2*log2(e).
// sig(i)*tanh(g) = (eg-1)/((1+ei)(eg+1)); 8 trans + 12 VALU per unit.
__device__ __forceinline__ void lstm_act(float gi, float gf, float gg, float go,
                                         float& cL, float& h) {
    float ef = EXP2(-gf);
    float fv = __builtin_amdgcn_rcpf(1.0f + ef);
    float ei = EXP2(-gi);
    float eg = EXP2(gg);
    float igL = fmaf(eg, L2E2, -L2E2) *
                __builtin_amdgcn_rcpf((1.0f + ei) * (eg + 1.0f));
    cL = fmaf(fv, cL, igL);
    float eo = EXP2(-go);
    float ec = EXP2(cL);
    h = (ec - 1.0f) * __builtin_amdgcn_rcpf((1.0f + eo) * (ec + 1.0f));
}

extern "C" __global__ void init_ws_k(u64* flags) {
    int i = blockIdx.x * 256 + threadIdx.x;
    if (i < 8192) flags[i] = 0;
}

extern "C" __global__ void __launch_bounds__(NT, 2)
lstm2_pair(const float* __restrict__ x,
           const float* __restrict__ Wih0, const float* __restrict__ Whh0,
           const float* __restrict__ bih0, const float* __restrict__ bhh0,
           const float* __restrict__ Wih1, const float* __restrict__ Whh1,
           const float* __restrict__ bih1, const float* __restrict__ bhh1,
           const float* __restrict__ Wc1,  const float* __restrict__ bc1,
           const float* __restrict__ Wc2,  const float* __restrict__ bc2,
           float* __restrict__ out, char* __restrict__ ws,
           int T, int groups, int slots)
{
    // recurrent h frags (f16), double buffered: [par][kf][row][j]
    // rows with (row&15)>=8 carry garbage (cols 8-15 of the N-tile) — they
    // only ever multiply into C cols 8-15, which are never consumed.
    __shared__ __align__(16) f16 bBuf[2][2][64][8];      // 4 KB
    __shared__ float xs[XCH][16];                        // 16 KB (cols 8-15 unused)
    __shared__ float hf[16][HD];                         // final h1 (rows 8-15 unused)
    __shared__ float hid[16][HD / 2];

    const int tid  = threadIdx.x;
    const int wave = tid >> 6;
    const int lane = tid & 63;
    const int q    = lane >> 4;
    const int n    = lane & 15;
    const int role  = blockIdx.x / groups;     // 0 = layer0 producer, 1 = layer1 consumer
    const int group = blockIdx.x % groups;     // pair (g, groups+g) -> same XCD (mod 8)
    const int b0    = group * GW;
    const int smask = slots - 1;

    u64* prodF = (u64*)(ws + (size_t)group * 128);
    u64* consF = (u64*)(ws + 32768 + (size_t)group * 128);
    char* ringG = ws + 65536 + (size_t)group * ((size_t)slots * PSZ);

    { int* p = (int*)&bBuf[0][0][0][0];
      for (int i = tid; i < 1024; i += NT) p[i] = 0; }

    const int gA  = n & 3;              // gate of A-tile row (gate-interleaved)
    const int tt0 = 2 * wave;           // this wave's 2 tiles
    const int kfL = wave >> 2;          // publish kf
    const int qk  = wave & 3;
    const int row = qk * 16 + n;        // publish row
    const f32x4 z4 = {0.f, 0.f, 0.f, 0.f};
    // gate 2 (tanh) rows/bias carry 2*log2e, sigmoid gates log2e.
    const float scA = (gA == 2) ? L2E2 : L2E;

    if (role == 0) {
        // ============ producer: layer 0, K=64, pure f16 ============
        f16x8 Ahi[4];
        f32x4 bias[2], wxv[2];
#pragma unroll
        for (int u = 0; u < 2; ++u) {
            const int tt = tt0 + u;
            const int rowA = gA * HD + tt * 4 + (n >> 2);
#pragma unroll
            for (int kf = 0; kf < 2; ++kf) {
                f16x8 hi;
#pragma unroll
                for (int j = 0; j < 8; ++j)
                    hi[j] = (f16)(Whh0[(size_t)rowA * HD + kinv(kf * 32 + q * 8 + j)] * scA);
                Ahi[u * 2 + kf] = hi;
            }
            const int uc = tt * 4 + q;
#pragma unroll
            for (int g = 0; g < 4; ++g) {
                float sg = (g == 2) ? L2E2 : L2E;
                bias[u][g] = (bih0[g * HD + uc] + bhh0[g * HD + uc]) * sg;
                wxv[u][g]  = Wih0[g * HD + uc] * sg;
            }
        }
        float c[2] = {0.f, 0.f};
        u64 cfcache = 0;
        __syncthreads();

#pragma unroll 1
        for (int t = 0; t < T; ++t) {
            // counted-vmcnt flag release for the PREVIOUS chunk, one step in.
            if ((t & (CHUNK - 1)) == 1 && t > CHUNK) {
                asm volatile("s_waitcnt vmcnt(4)" ::: "memory");
                if (lane == 0)
                    __hip_atomic_fetch_add(prodF, 1ull,
                                           __ATOMIC_RELAXED, __HIP_MEMORY_SCOPE_AGENT);
            }
            if ((t & (XCH - 1)) == 0) {       // stage next x chunk
                // GW*XCH/4 == 512 == NT: exactly one float4 per thread
                int bb = tid >> 6, t4 = (tid & 63) * 4;
                if (bb < GW && t + t4 < T) {
                    float4 v = *(const float4*)&x[(size_t)(b0 + bb) * T + t + t4];
                    xs[t4 + 0][bb] = v.x; xs[t4 + 1][bb] = v.y;
                    xs[t4 + 2][bb] = v.z; xs[t4 + 3][bb] = v.w;
                }
                BAR_LGKM();
            }
            // ring-full throttle (chunk granular; cached poll).
            if ((t & (CHUNK - 1)) == 0 && t + CHUNK > slots) {
                u64 need = (u64)(t + CHUNK - slots);
                if (tid == 0 && cfcache < need) cfcache = pollflag(consF, need);
                BAR_LGKM();
            }

            const int par = t & 1;
            f16x8 bh0 = *(const f16x8*)&bBuf[par][0][lane][0];
            f16x8 bh1 = *(const f16x8*)&bBuf[par][1][lane][0];
            float xv = xs[t & (XCH - 1)][n];   // cols 8-15 garbage: contained
            float hq[2];
#pragma unroll
            for (int u = 0; u < 2; ++u) {
                f32x4 Ghi;
#pragma unroll
                for (int g = 0; g < 4; ++g) Ghi[g] = fmaf(wxv[u][g], xv, bias[u][g]);
                Ghi = MFMA(Ahi[u * 2 + 0], bh0, Ghi);
                Ghi = MFMA(Ahi[u * 2 + 1], bh1, Ghi);
                lstm_act(Ghi[0], Ghi[1], Ghi[2], Ghi[3], c[u], hq[u]);
            }
            // publish h0(t): LDS (own next step) + ring via sc1 store (LLC).
            // Only valid-batch lanes (n<8) store to the ring.
            u32 pH = packf16((f16)hq[0], (f16)hq[1]);
            *(u32*)&bBuf[par ^ 1][kfL][row][2 * q] = pH;
            if (n < GW) {
                char* sb = ringG + (size_t)(t & smask) * PSZ;
                __hip_atomic_store((u32*)(sb + (kfL * 64 + row) * 16 + q * 4), pH,
                                   __ATOMIC_RELAXED, __HIP_MEMORY_SCOPE_AGENT);
            }
            BAR_LGKM();   // LDS visibility only; vmcnt stays outstanding
        }
        // final chunk release: full drain (loop is over, nothing to hide under)
        asm volatile("s_waitcnt vmcnt(0)" ::: "memory");
        if (lane == 0)
            __hip_atomic_fetch_add(prodF, 1ull,
                                   __ATOMIC_RELAXED, __HIP_MEMORY_SCOPE_AGENT);
    } else {
        // ============ consumer: layer 1, K=128, pure f16 ============
        f16x8 Ahi[8];
        f32x4 bias[2];
#pragma unroll
        for (int u = 0; u < 2; ++u) {
            const int tt = tt0 + u;
            const int rowA = gA * HD + tt * 4 + (n >> 2);
#pragma unroll
            for (int kf = 0; kf < 4; ++kf) {
                f16x8 hi;
#pragma unroll
                for (int j = 0; j < 8; ++j)
                    hi[j] = (f16)(((kf < 2)
                        ? Wih1[(size_t)rowA * HD + kinv(kf * 32 + q * 8 + j)]
                        : Whh1[(size_t)rowA * HD + kinv((kf - 2) * 32 + q * 8 + j)]) * scA);
                Ahi[u * 4 + kf] = hi;
            }
            const int uc = tt * 4 + q;
#pragma unroll
            for (int g = 0; g < 4; ++g)
                bias[u][g] = (bih1[g * HD + uc] + bhh1[g * HD + uc])
                             * ((g == 2) ? L2E2 : L2E);
        }
        float c[2] = {0.f, 0.f};
        f16x8 pfh[2][2];   // prefetched h0 frags, 2 slots in flight

        auto loadslot = [&](int s, int buf) {   // sc1 (LLC) loads, L1/L2 bypass
            char* sb = ringG + (size_t)(s & smask) * PSZ + (size_t)lane * 16;
#pragma unroll
            for (int kf = 0; kf < 2; ++kf) {
                union { u64 d[2]; f16x8 v; } Uh;
                u64* ph = (u64*)(sb + kf * 1024);
                Uh.d[0] = __hip_atomic_load(ph,     __ATOMIC_RELAXED, __HIP_MEMORY_SCOPE_AGENT);
                Uh.d[1] = __hip_atomic_load(ph + 1, __ATOMIC_RELAXED, __HIP_MEMORY_SCOPE_AGENT);
                pfh[buf][kf] = Uh.v;
            }
        };
        u64 pfcache = 0;
        __syncthreads();

#pragma unroll 1
        for (int cs = 0; cs < T; cs += CHUNK) {
            // need chunk (cs/8 + 1) fully acked (prefetch reaches cs+9):
            // flag >= cs+16 in sum-counter units (8 waves x chunks).
            u64 need = (u64)((cs + 16 > T) ? T : cs + 16);
            if (tid == 0 && pfcache < need) pfcache = pollflag(prodF, need);
            BAR_LGKM();                                        // release all waves
            if (cs == 0) { loadslot(0, 0); loadslot(1, 1); }
#pragma unroll
            for (int cc = 0; cc < CHUNK; ++cc) {
                const int s = cs + cc;
                const int buf = s & 1, par = s & 1;
                f16x8 ch0 = *(const f16x8*)&bBuf[par][0][lane][0];
                f16x8 ch1 = *(const f16x8*)&bBuf[par][1][lane][0];
                float hq[2];
#pragma unroll
                for (int u = 0; u < 2; ++u) {
                    // two parallel 2-deep chains: pf-side (regs) + ch-side.
                    f32x4 GA = MFMA(Ahi[u * 4 + 0], pfh[buf][0], bias[u]);
                    GA = MFMA(Ahi[u * 4 + 1], pfh[buf][1], GA);
                    f32x4 GB = MFMA(Ahi[u * 4 + 2], ch0, z4);
                    GB = MFMA(Ahi[u * 4 + 3], ch1, GB);
                    lstm_act(GA[0] + GB[0], GA[1] + GB[1],
                             GA[2] + GB[2], GA[3] + GB[3], c[u], hq[u]);
                }
                // prefetch slot s+2 into the buf being retired this step;
                // stays in flight across the lgkm-only barrier.
                if (s + 2 < T) loadslot(s + 2, buf);
                u32 pH = packf16((f16)hq[0], (f16)hq[1]);
                *(u32*)&bBuf[par ^ 1][kfL][row][2 * q] = pH;
                if (s == T - 1) {
                    hf[n][(tt0 + 0) * 4 + q] = hq[0];
                    hf[n][(tt0 + 1) * 4 + q] = hq[1];
                }
                BAR_LGKM();
            }
            // chunk's ring reads were consumed (data-dep waits) before the
            // final per-step barrier; safe to signal with a relaxed store.
            if (tid == 0)
                __hip_atomic_store(consF, (u64)(cs + CHUNK),
                                   __ATOMIC_RELAXED, __HIP_MEMORY_SCOPE_AGENT);
        }

        // classifier: relu(h1 @ Wc1^T + bc1) @ Wc2^T + bc2
        __syncthreads();
        if (tid < GW * 32) {
            int nn = tid >> 5, m = tid & 31;
            float acc = bc1[m];
            const float* wr = Wc1 + m * HD;
#pragma unroll
            for (int k = 0; k < HD; ++k) acc += wr[k] * hf[nn][k];
            hid[nn][m] = fmaxf(acc, 0.0f);
        }
        __syncthreads();
        if (tid < GW) {
            float acc = bc2[0];
#pragma unroll
            for (int k = 0; k < HD / 2; ++k) acc += Wc2[k] * hid[tid][k];
            out[b0 + tid] = acc;
        }
    }
}

extern "C" void kernel_launch(void* const* d_in, const int* in_sizes, int n_in,
                              void* d_out, int out_size, void* d_ws, size_t ws_size,
                              hipStream_t stream) {
    const float* x    = (const float*)d_in[0];
    const float* Wih0 = (const float*)d_in[1];
    const float* Whh0 = (const float*)d_in[2];
    const float* bih0 = (const float*)d_in[3];
    const float* bhh0 = (const float*)d_in[4];
    const float* Wih1 = (const float*)d_in[5];
    const float* Whh1 = (const float*)d_in[6];
    const float* bih1 = (const float*)d_in[7];
    const float* bhh1 = (const float*)d_in[8];
    const float* Wc1  = (const float*)d_in[9];
    const float* bc1  = (const float*)d_in[10];
    const float* Wc2  = (const float*)d_in[11];
    const float* bc2  = (const float*)d_in[12];

    const int B = out_size;            // output [B,1]
    const int T = in_sizes[0] / B;     // x is [B,T,1]
    const int groups = B / GW;         // 256

    // ring depth from ws_size: 8 slots minimum (65536 + 256*8*2048 = 4.26 MB)
    int slots = 8;
    while (slots < 64 &&
           65536 + (size_t)groups * (size_t)(slots * 2) * 2048 <= ws_size)
        slots *= 2;

    hipLaunchKernelGGL(init_ws_k, dim3(32), dim3(256), 0, stream, (u64*)d_ws);
    hipLaunchKernelGGL(lstm2_pair, dim3(2 * groups), dim3(NT), 0, stream,
                       x, Wih0, Whh0, bih0, bhh0,
                       Wih1, Whh1, bih1, bhh1,
                       Wc1, bc1, Wc2, bc2,
                       (float*)d_out, (char*)d_ws, T, groups, slots);
}

// Round 11
// 603.101 us; speedup vs baseline: 1.2911x; 1.2911x over previous
//
#include <hip/hip_runtime.h>

typedef _Float16 f16;
typedef _Float16 f16x8 __attribute__((ext_vector_type(8)));
typedef float    f32x4 __attribute__((ext_vector_type(4)));
typedef unsigned int       u32;
typedef unsigned short     u16;
typedef unsigned long long u64;

#define HD    64
#define GW    16      // batches per group (full N-tile)
#define NT    512     // 8 waves
#define CHUNK 16      // steps per flag update (halved sync overhead)
#define XCH   256     // x staging chunk (timesteps)
#define L2E   1.44269504088896340736f
#define L2E2  2.88539008177792681472f

// Barrier that waits ONLY on LDS (lgkmcnt) — in-flight global sc1 traffic
// (vmcnt) stays outstanding across it.
#define BAR_LGKM() asm volatile("s_waitcnt lgkmcnt(0)\ns_barrier" ::: "memory")

#if __has_builtin(__builtin_amdgcn_exp2f)
#define EXP2(x) __builtin_amdgcn_exp2f(x)
#else
#define EXP2(x) __expf((x) * 0.69314718055994530942f)
#endif

__device__ __forceinline__ f32x4 MFMA(f16x8 a, f16x8 b, f32x4 c) {
    return __builtin_amdgcn_mfma_f32_16x16x32_f16(a, b, c, 0, 0, 0);
}
// unit->k permutation (conflict-free packed publishes); kinv maps k -> unit
__device__ __forceinline__ int kinv(int k) {
    int kf = k >> 5, qk = (k >> 3) & 3, j = k & 7;
    int tile = (kf << 3) | (qk << 1) | (j & 1);
    return tile * 4 + (j >> 1);
}
__device__ __forceinline__ u32 packf16(f16 a, f16 b) {
    union { f16 h[2]; u32 u; } x; x.h[0] = a; x.h[1] = b; return x.u;
}
// relaxed poll, NO acquire fence: ring data read via sc1 (LLC) loads.
__device__ __forceinline__ u64 pollflag(u64* p, u64 need) {
    int guard = 0; u64 v;
    while ((v = __hip_atomic_load(p, __ATOMIC_RELAXED, __HIP_MEMORY_SCOPE_AGENT)) < need) {
        __builtin_amdgcn_s_sleep(2);
        if (++guard > (1 << 20)) break;   // fail visibly, don't hang
    }
    return v;
}

// Gate inputs pre-scaled: gi,gf,go by log2(e); gg by 2*log2(e).
// Cell state kept PRE-SCALED: cL = c * 2*log2(e).
// sig(i)*tanh(g) = (eg-1)/((1+ei)(eg+1)); 8 trans + 12 VALU per unit.
__device__ __forceinline__ void lstm_act(float gi, float gf, float gg, float go,
                                         float& cL, float& h) {
    float ef = EXP2(-gf);
    float fv = __builtin_amdgcn_rcpf(1.0f + ef);
    float ei = EXP2(-gi);
    float eg = EXP2(gg);
    float igL = fmaf(eg, L2E2, -L2E2) *
                __builtin_amdgcn_rcpf((1.0f + ei) * (eg + 1.0f));
    cL = fmaf(fv, cL, igL);
    float eo = EXP2(-go);
    float ec = EXP2(cL);
    h = (ec - 1.0f) * __builtin_amdgcn_rcpf((1.0f + eo) * (ec + 1.0f));
}

extern "C" __global__ void init_ws_k(u64* flags) {
    int i = blockIdx.x * 256 + threadIdx.x;
    if (i < 8192) flags[i] = 0;
}

extern "C" __global__ void __launch_bounds__(NT, 2)
lstm2_pair(const float* __restrict__ x,
           const float* __restrict__ Wih0, const float* __restrict__ Whh0,
           const float* __restrict__ bih0, const float* __restrict__ bhh0,
           const float* __restrict__ Wih1, const float* __restrict__ Whh1,
           const float* __restrict__ bih1, const float* __restrict__ bhh1,
           const float* __restrict__ Wc1,  const float* __restrict__ bc1,
           const float* __restrict__ Wc2,  const float* __restrict__ bc2,
           float* __restrict__ out, char* __restrict__ ws,
           int T, int groups, int slots)
{
    // recurrent h frags (f16), double buffered: [par][kf][row][j]
    __shared__ __align__(16) f16 bBuf[2][2][64][8];      // 4 KB
    __shared__ float xs[XCH][GW];                        // 16 KB (producer only)
    __shared__ float hf[GW][HD];                         // final h1 (consumer)
    __shared__ float hid[GW][HD / 2];

    const int tid  = threadIdx.x;
    const int wave = tid >> 6;
    const int lane = tid & 63;
    const int q    = lane >> 4;
    const int n    = lane & 15;
    const int role  = blockIdx.x / groups;     // 0 = layer0 producer, 1 = layer1 consumer
    const int group = blockIdx.x % groups;     // pair (g, groups+g) -> same XCD (mod 8)
    const int b0    = group * GW;
    const int smask = slots - 1;

    u64* prodF = (u64*)(ws + (size_t)group * 128);
    u64* consF = (u64*)(ws + 32768 + (size_t)group * 128);
    char* ringG = ws + 65536 + (size_t)group * ((size_t)slots * 4096);

    { int* p = (int*)&bBuf[0][0][0][0];
      for (int i = tid; i < 1024; i += NT) p[i] = 0; }

    const int gA  = n & 3;              // gate of A-tile row (gate-interleaved)
    const int tt0 = 2 * wave;           // this wave's 2 tiles
    const int kfL = wave >> 2;          // publish kf
    const int qk  = wave & 3;
    const int row = qk * 16 + n;        // publish row
    const f32x4 z4 = {0.f, 0.f, 0.f, 0.f};
    // gate 2 (tanh) rows/bias carry 2*log2e, sigmoid gates log2e.
    const float scA = (gA == 2) ? L2E2 : L2E;

    if (role == 0) {
        // ============ producer: layer 0, K=64, pure f16 ============
        f16x8 Ahi[4];
        f32x4 bias[2], wxv[2];
#pragma unroll
        for (int u = 0; u < 2; ++u) {
            const int tt = tt0 + u;
            const int rowA = gA * HD + tt * 4 + (n >> 2);
#pragma unroll
            for (int kf = 0; kf < 2; ++kf) {
                f16x8 hi;
#pragma unroll
                for (int j = 0; j < 8; ++j)
                    hi[j] = (f16)(Whh0[(size_t)rowA * HD + kinv(kf * 32 + q * 8 + j)] * scA);
                Ahi[u * 2 + kf] = hi;
            }
            const int uc = tt * 4 + q;
#pragma unroll
            for (int g = 0; g < 4; ++g) {
                float sg = (g == 2) ? L2E2 : L2E;
                bias[u][g] = (bih0[g * HD + uc] + bhh0[g * HD + uc]) * sg;
                wxv[u][g]  = Wih0[g * HD + uc] * sg;
            }
        }
        float c[2] = {0.f, 0.f};
        u64 cfcache = 0;
        __syncthreads();

#pragma unroll 1
        for (int t = 0; t < T; ++t) {
            // counted-vmcnt flag release for the PREVIOUS chunk, one step in.
            // Flag = sum-counter: 8 waves per 16-step chunk.
            if ((t & (CHUNK - 1)) == 1 && t > CHUNK) {
                asm volatile("s_waitcnt vmcnt(4)" ::: "memory");
                if (lane == 0)
                    __hip_atomic_fetch_add(prodF, 1ull,
                                           __ATOMIC_RELAXED, __HIP_MEMORY_SCOPE_AGENT);
            }
            if ((t & (XCH - 1)) == 0) {       // stage next x chunk
                // GW*XCH/4 == 1024; two float4 per thread
                for (int i = tid; i < GW * XCH / 4; i += NT) {
                    int bb = i >> 6, t4 = (i & 63) * 4;
                    if (t + t4 < T) {
                        float4 v = *(const float4*)&x[(size_t)(b0 + bb) * T + t + t4];
                        xs[t4 + 0][bb] = v.x; xs[t4 + 1][bb] = v.y;
                        xs[t4 + 2][bb] = v.z; xs[t4 + 3][bb] = v.w;
                    }
                }
                BAR_LGKM();
            }
            // ring-full throttle (chunk granular; cached poll, step units).
            if ((t & (CHUNK - 1)) == 0 && t + CHUNK > slots) {
                u64 need = (u64)(t + CHUNK - slots);
                if (tid == 0 && cfcache < need) cfcache = pollflag(consF, need);
                BAR_LGKM();
            }

            const int par = t & 1;
            f16x8 bh0 = *(const f16x8*)&bBuf[par][0][lane][0];
            f16x8 bh1 = *(const f16x8*)&bBuf[par][1][lane][0];
            float xv = xs[t & (XCH - 1)][n];
            float hq[2];
#pragma unroll
            for (int u = 0; u < 2; ++u) {
                f32x4 Ghi;
#pragma unroll
                for (int g = 0; g < 4; ++g) Ghi[g] = fmaf(wxv[u][g], xv, bias[u][g]);
                Ghi = MFMA(Ahi[u * 2 + 0], bh0, Ghi);
                Ghi = MFMA(Ahi[u * 2 + 1], bh1, Ghi);
                lstm_act(Ghi[0], Ghi[1], Ghi[2], Ghi[3], c[u], hq[u]);
            }
            // publish h0(t): LDS (own next step) + ring via sc1 store (LLC).
            u32 pH = packf16((f16)hq[0], (f16)hq[1]);
            *(u32*)&bBuf[par ^ 1][kfL][row][2 * q] = pH;
            char* sb = ringG + (size_t)(t & smask) * 4096;
            __hip_atomic_store((u32*)(sb + (kfL * 64 + row) * 16 + q * 4), pH,
                               __ATOMIC_RELAXED, __HIP_MEMORY_SCOPE_AGENT);
            BAR_LGKM();   // LDS visibility only; vmcnt stays outstanding
        }
        // final chunk release: full drain (loop is over, nothing to hide under)
        asm volatile("s_waitcnt vmcnt(0)" ::: "memory");
        if (lane == 0)
            __hip_atomic_fetch_add(prodF, 1ull,
                                   __ATOMIC_RELAXED, __HIP_MEMORY_SCOPE_AGENT);
    } else {
        // ============ consumer: layer 1, K=128, pure f16 ============
        f16x8 Ahi[8];
        f32x4 bias[2];
#pragma unroll
        for (int u = 0; u < 2; ++u) {
            const int tt = tt0 + u;
            const int rowA = gA * HD + tt * 4 + (n >> 2);
#pragma unroll
            for (int kf = 0; kf < 4; ++kf) {
                f16x8 hi;
#pragma unroll
                for (int j = 0; j < 8; ++j)
                    hi[j] = (f16)(((kf < 2)
                        ? Wih1[(size_t)rowA * HD + kinv(kf * 32 + q * 8 + j)]
                        : Whh1[(size_t)rowA * HD + kinv((kf - 2) * 32 + q * 8 + j)]) * scA);
                Ahi[u * 4 + kf] = hi;
            }
            const int uc = tt * 4 + q;
#pragma unroll
            for (int g = 0; g < 4; ++g)
                bias[u][g] = (bih1[g * HD + uc] + bhh1[g * HD + uc])
                             * ((g == 2) ? L2E2 : L2E);
        }
        float c[2] = {0.f, 0.f};
        f16x8 pfh[2][2];   // prefetched h0 frags, 2 slots in flight

        auto loadslot = [&](int s, int buf) {   // sc1 (LLC) loads, L1/L2 bypass
            char* sb = ringG + (size_t)(s & smask) * 4096 + (size_t)lane * 16;
#pragma unroll
            for (int kf = 0; kf < 2; ++kf) {
                union { u64 d[2]; f16x8 v; } Uh;
                u64* ph = (u64*)(sb + kf * 1024);
                Uh.d[0] = __hip_atomic_load(ph,     __ATOMIC_RELAXED, __HIP_MEMORY_SCOPE_AGENT);
                Uh.d[1] = __hip_atomic_load(ph + 1, __ATOMIC_RELAXED, __HIP_MEMORY_SCOPE_AGENT);
                pfh[buf][kf] = Uh.v;
            }
        };
        u64 pfcache = 0;
        __syncthreads();

#pragma unroll 1
        for (int cs = 0; cs < T; cs += CHUNK) {
            // prefetch reaches step cs+CHUNK+1 -> need chunks covering cs+18:
            // flag >= 8*(cs/16 + 2), capped at total T/2.
            u64 need = (u64)(8 * (cs / CHUNK + 2));
            u64 cap  = (u64)(T / 2);
            if (need > cap) need = cap;
            if (tid == 0 && pfcache < need) pfcache = pollflag(prodF, need);
            BAR_LGKM();                                        // release all waves
            if (cs == 0) { loadslot(0, 0); loadslot(1, 1); }
#pragma unroll
            for (int cc = 0; cc < CHUNK; ++cc) {
                const int s = cs + cc;
                const int buf = s & 1, par = s & 1;
                f16x8 ch0 = *(const f16x8*)&bBuf[par][0][lane][0];
                f16x8 ch1 = *(const f16x8*)&bBuf[par][1][lane][0];
                // Gate sums for BOTH units first (MFMA-latency section),
                // then prefetch issue, then the act chains — keeps the sc1
                // loads flying under act + barrier + next ds_read.
                f32x4 gsum[2];
#pragma unroll
                for (int u = 0; u < 2; ++u) {
                    // GA: pf-side 2-deep (operands in regs, slack-fed).
                    // GB: own-recurrence split into TWO parallel 1-deep
                    // chains — the critical path loses one MFMA latency.
                    f32x4 GA = MFMA(Ahi[u * 4 + 0], pfh[buf][0], bias[u]);
                    GA = MFMA(Ahi[u * 4 + 1], pfh[buf][1], GA);
                    f32x4 GB0 = MFMA(Ahi[u * 4 + 2], ch0, z4);
                    f32x4 GB1 = MFMA(Ahi[u * 4 + 3], ch1, z4);
#pragma unroll
                    for (int g = 0; g < 4; ++g)
                        gsum[u][g] = (GA[g] + GB0[g]) + GB1[g];
                }
                if (s + 2 < T) loadslot(s + 2, buf);
                float hq[2];
#pragma unroll
                for (int u = 0; u < 2; ++u)
                    lstm_act(gsum[u][0], gsum[u][1], gsum[u][2], gsum[u][3],
                             c[u], hq[u]);
                u32 pH = packf16((f16)hq[0], (f16)hq[1]);
                *(u32*)&bBuf[par ^ 1][kfL][row][2 * q] = pH;
                if (s == T - 1) {
                    hf[n][(tt0 + 0) * 4 + q] = hq[0];
                    hf[n][(tt0 + 1) * 4 + q] = hq[1];
                }
                BAR_LGKM();
            }
            // chunk's ring reads were consumed (data-dep waits) before the
            // final per-step barrier; safe to signal with a relaxed store.
            if (tid == 0)
                __hip_atomic_store(consF, (u64)(cs + CHUNK),
                                   __ATOMIC_RELAXED, __HIP_MEMORY_SCOPE_AGENT);
        }

        // classifier: relu(h1 @ Wc1^T + bc1) @ Wc2^T + bc2
        __syncthreads();
        if (tid < GW * 32) {
            int nn = tid >> 5, m = tid & 31;
            float acc = bc1[m];
            const float* wr = Wc1 + m * HD;
#pragma unroll
            for (int k = 0; k < HD; ++k) acc += wr[k] * hf[nn][k];
            hid[nn][m] = fmaxf(acc, 0.0f);
        }
        __syncthreads();
        if (tid < GW) {
            float acc = bc2[0];
#pragma unroll
            for (int k = 0; k < HD / 2; ++k) acc += Wc2[k] * hid[tid][k];
            out[b0 + tid] = acc;
        }
    }
}

extern "C" void kernel_launch(void* const* d_in, const int* in_sizes, int n_in,
                              void* d_out, int out_size, void* d_ws, size_t ws_size,
                              hipStream_t stream) {
    const float* x    = (const float*)d_in[0];
    const float* Wih0 = (const float*)d_in[1];
    const float* Whh0 = (const float*)d_in[2];
    const float* bih0 = (const float*)d_in[3];
    const float* bhh0 = (const float*)d_in[4];
    const float* Wih1 = (const float*)d_in[5];
    const float* Whh1 = (const float*)d_in[6];
    const float* bih1 = (const float*)d_in[7];
    const float* bhh1 = (const float*)d_in[8];
    const float* Wc1  = (const float*)d_in[9];
    const float* bc1  = (const float*)d_in[10];
    const float* Wc2  = (const float*)d_in[11];
    const float* bc2  = (const float*)d_in[12];

    const int B = out_size;            // output [B,1]
    const int T = in_sizes[0] / B;     // x is [B,T,1]
    const int groups = B / GW;         // 128

    // ring depth from ws_size: 16 slots minimum (>= CHUNK); deeper if room
    int slots = 16;
    while (slots < 64 &&
           65536 + (size_t)groups * (size_t)(slots * 2) * 4096 <= ws_size)
        slots *= 2;

    hipLaunchKernelGGL(init_ws_k, dim3(32), dim3(256), 0, stream, (u64*)d_ws);
    hipLaunchKernelGGL(lstm2_pair, dim3(2 * groups), dim3(NT), 0, stream,
                       x, Wih0, Whh0, bih0, bhh0,
                       Wih1, Whh1, bih1, bhh1,
                       Wc1, bc1, Wc2, bc2,
                       (float*)d_out, (char*)d_ws, T, groups, slots);
}

// Round 12
// 549.807 us; speedup vs baseline: 1.4162x; 1.0969x over previous
//
#include <hip/hip_runtime.h>

typedef _Float16 f16;
typedef _Float16 f16x8 __attribute__((ext_vector_type(8)));
typedef float    f32x4 __attribute__((ext_vector_type(4)));
typedef unsigned int       u32;
typedef unsigned long long u64;

#define HD    64
#define GW    16      // batches per group (full N-tile, zero padding)
#define NT    512     // 8 waves
#define CHUNK 8       // steps per flag update
#define XCH   256     // x staging chunk (timesteps)
#define L2E   1.44269504088896340736f
#define L2E2  2.88539008177792681472f

// Barrier that waits ONLY on LDS (lgkmcnt) — in-flight global sc1 traffic
// (vmcnt) stays outstanding across it.
#define BAR_LGKM() asm volatile("s_waitcnt lgkmcnt(0)\ns_barrier" ::: "memory")

#if __has_builtin(__builtin_amdgcn_exp2f)
#define EXP2(x) __builtin_amdgcn_exp2f(x)
#else
#define EXP2(x) __expf((x) * 0.69314718055994530942f)
#endif

__device__ __forceinline__ f32x4 MFMA(f16x8 a, f16x8 b, f32x4 c) {
    return __builtin_amdgcn_mfma_f32_16x16x32_f16(a, b, c, 0, 0, 0);
}
// unit->k permutation (conflict-free packed publishes); kinv maps k -> unit
__device__ __forceinline__ int kinv(int k) {
    int kf = k >> 5, qk = (k >> 3) & 3, j = k & 7;
    int tile = (kf << 3) | (qk << 1) | (j & 1);
    return tile * 4 + (j >> 1);
}
__device__ __forceinline__ u32 packf16(f16 a, f16 b) {
    union { f16 h[2]; u32 u; } x; x.h[0] = a; x.h[1] = b; return x.u;
}
// relaxed poll, NO acquire fence: ring data read via sc1 (LLC) loads.
__device__ __forceinline__ u64 pollflag(u64* p, u64 need) {
    int guard = 0; u64 v;
    while ((v = __hip_atomic_load(p, __ATOMIC_RELAXED, __HIP_MEMORY_SCOPE_AGENT)) < need) {
        __builtin_amdgcn_s_sleep(2);
        if (++guard > (1 << 20)) break;   // fail visibly, don't hang
    }
    return v;
}

// Gate inputs pre-scaled: gi,gf,go by log2(e); gg by 2*log2(e).
// Cell state kept PRE-SCALED: cL = c * 2*log2(e).
// sig(i)*tanh(g) = (eg-1)/((1+ei)(eg+1)); 8 trans + 12 VALU per unit.
__device__ __forceinline__ void lstm_act(float gi, float gf, float gg, float go,
                                         float& cL, float& h) {
    float ef = EXP2(-gf);
    float fv = __builtin_amdgcn_rcpf(1.0f + ef);
    float ei = EXP2(-gi);
    float eg = EXP2(gg);
    float igL = fmaf(eg, L2E2, -L2E2) *
                __builtin_amdgcn_rcpf((1.0f + ei) * (eg + 1.0f));
    cL = fmaf(fv, cL, igL);
    float eo = EXP2(-go);
    float ec = EXP2(cL);
    h = (ec - 1.0f) * __builtin_amdgcn_rcpf((1.0f + eo) * (ec + 1.0f));
}

extern "C" __global__ void init_ws_k(u64* flags) {
    int i = blockIdx.x * 256 + threadIdx.x;
    if (i < 8192) flags[i] = 0;
}

extern "C" __global__ void __launch_bounds__(NT, 2)
lstm2_pair(const float* __restrict__ x,
           const float* __restrict__ Wih0, const float* __restrict__ Whh0,
           const float* __restrict__ bih0, const float* __restrict__ bhh0,
           const float* __restrict__ Wih1, const float* __restrict__ Whh1,
           const float* __restrict__ bih1, const float* __restrict__ bhh1,
           const float* __restrict__ Wc1,  const float* __restrict__ bc1,
           const float* __restrict__ Wc2,  const float* __restrict__ bc2,
           float* __restrict__ out, char* __restrict__ ws,
           int T, int groups, int slots)
{
    // recurrent h frags (f16, single precision), double buffered:
    // [par][kf][row][j]
    __shared__ __align__(16) f16 bBuf[2][2][64][8];      // 4 KB
    __shared__ float xs[XCH][GW];                        // 16 KB (producer only)
    __shared__ float hf[GW][HD];                         // final h1 (consumer)
    __shared__ float hid[GW][HD / 2];

    const int tid  = threadIdx.x;
    const int wave = tid >> 6;
    const int lane = tid & 63;
    const int q    = lane >> 4;
    const int n    = lane & 15;
    const int role  = blockIdx.x / groups;     // 0 = layer0 producer, 1 = layer1 consumer
    const int group = blockIdx.x % groups;     // pair (g, groups+g) -> same XCD (mod 8)
    const int b0    = group * GW;
    const int smask = slots - 1;

    u64* prodF = (u64*)(ws + (size_t)group * 128);
    u64* consF = (u64*)(ws + 32768 + (size_t)group * 128);
    char* ringG = ws + 65536 + (size_t)group * ((size_t)slots * 4096);

    { int* p = (int*)&bBuf[0][0][0][0];
      for (int i = tid; i < 1024; i += NT) p[i] = 0; }

    const int gA  = n & 3;              // gate of A-tile row (gate-interleaved)
    const int tt0 = 2 * wave;           // this wave's 2 tiles
    const int kfL = wave >> 2;          // publish kf
    const int qk  = wave & 3;
    const int row = qk * 16 + n;        // publish row
    const f32x4 z4 = {0.f, 0.f, 0.f, 0.f};
    // gate 2 (tanh) rows/bias carry 2*log2e, sigmoid gates log2e.
    const float scA = (gA == 2) ? L2E2 : L2E;

    if (role == 0) {
        // ============ producer: layer 0, K=64, pure f16 ============
        f16x8 Ahi[4];
        f32x4 bias[2], wxv[2];
#pragma unroll
        for (int u = 0; u < 2; ++u) {
            const int tt = tt0 + u;
            const int rowA = gA * HD + tt * 4 + (n >> 2);
#pragma unroll
            for (int kf = 0; kf < 2; ++kf) {
                f16x8 hi;
#pragma unroll
                for (int j = 0; j < 8; ++j)
                    hi[j] = (f16)(Whh0[(size_t)rowA * HD + kinv(kf * 32 + q * 8 + j)] * scA);
                Ahi[u * 2 + kf] = hi;
            }
            const int uc = tt * 4 + q;
#pragma unroll
            for (int g = 0; g < 4; ++g) {
                float sg = (g == 2) ? L2E2 : L2E;
                bias[u][g] = (bih0[g * HD + uc] + bhh0[g * HD + uc]) * sg;
                wxv[u][g]  = Wih0[g * HD + uc] * sg;
            }
        }
        float c[2] = {0.f, 0.f};
        u64 cfcache = 0;
        __syncthreads();

#pragma unroll 1
        for (int t = 0; t < T; ++t) {
            // counted-vmcnt flag release for the PREVIOUS chunk, one step in.
            if ((t & (CHUNK - 1)) == 1 && t > CHUNK) {
                asm volatile("s_waitcnt vmcnt(4)" ::: "memory");
                if (lane == 0)
                    __hip_atomic_fetch_add(prodF, 1ull,
                                           __ATOMIC_RELAXED, __HIP_MEMORY_SCOPE_AGENT);
            }
            if ((t & (XCH - 1)) == 0) {       // stage next x chunk
                for (int i = tid; i < GW * XCH / 4; i += NT) {
                    int bb = i >> 6, t4 = (i & 63) * 4;
                    if (t + t4 < T) {
                        float4 v = *(const float4*)&x[(size_t)(b0 + bb) * T + t + t4];
                        xs[t4 + 0][bb] = v.x; xs[t4 + 1][bb] = v.y;
                        xs[t4 + 2][bb] = v.z; xs[t4 + 3][bb] = v.w;
                    }
                }
                BAR_LGKM();
            }
            // ring-full throttle (chunk granular; cached poll).
            if ((t & (CHUNK - 1)) == 0 && t + CHUNK > slots) {
                u64 need = (u64)(t + CHUNK - slots);
                if (tid == 0 && cfcache < need) cfcache = pollflag(consF, need);
                BAR_LGKM();
            }

            const int par = t & 1;
            f16x8 bh0 = *(const f16x8*)&bBuf[par][0][lane][0];
            f16x8 bh1 = *(const f16x8*)&bBuf[par][1][lane][0];
            float xv = xs[t & (XCH - 1)][n];
            float hq[2];
#pragma unroll
            for (int u = 0; u < 2; ++u) {
                f32x4 Ghi;
#pragma unroll
                for (int g = 0; g < 4; ++g) Ghi[g] = fmaf(wxv[u][g], xv, bias[u][g]);
                Ghi = MFMA(Ahi[u * 2 + 0], bh0, Ghi);
                Ghi = MFMA(Ahi[u * 2 + 1], bh1, Ghi);
                lstm_act(Ghi[0], Ghi[1], Ghi[2], Ghi[3], c[u], hq[u]);
            }
            // publish h0(t): LDS (own next step) + ring via sc1 store (LLC).
            // RTN casts — no systematic shrink of recurrent h.
            u32 pH = packf16((f16)hq[0], (f16)hq[1]);
            *(u32*)&bBuf[par ^ 1][kfL][row][2 * q] = pH;
            char* sb = ringG + (size_t)(t & smask) * 4096;
            __hip_atomic_store((u32*)(sb + (kfL * 64 + row) * 16 + q * 4), pH,
                               __ATOMIC_RELAXED, __HIP_MEMORY_SCOPE_AGENT);
            BAR_LGKM();   // LDS visibility only; vmcnt stays outstanding
        }
        // final chunk release: full drain (loop is over, nothing to hide under)
        asm volatile("s_waitcnt vmcnt(0)" ::: "memory");
        if (lane == 0)
            __hip_atomic_fetch_add(prodF, 1ull,
                                   __ATOMIC_RELAXED, __HIP_MEMORY_SCOPE_AGENT);
    } else {
        // ============ consumer: layer 1, K=128, pure f16 ============
        f16x8 Ahi[8];
        f32x4 bias[2];
#pragma unroll
        for (int u = 0; u < 2; ++u) {
            const int tt = tt0 + u;
            const int rowA = gA * HD + tt * 4 + (n >> 2);
#pragma unroll
            for (int kf = 0; kf < 4; ++kf) {
                f16x8 hi;
#pragma unroll
                for (int j = 0; j < 8; ++j)
                    hi[j] = (f16)(((kf < 2)
                        ? Wih1[(size_t)rowA * HD + kinv(kf * 32 + q * 8 + j)]
                        : Whh1[(size_t)rowA * HD + kinv((kf - 2) * 32 + q * 8 + j)]) * scA);
                Ahi[u * 4 + kf] = hi;
            }
            const int uc = tt * 4 + q;
#pragma unroll
            for (int g = 0; g < 4; ++g)
                bias[u][g] = (bih1[g * HD + uc] + bhh1[g * HD + uc])
                             * ((g == 2) ? L2E2 : L2E);
        }
        float c[2] = {0.f, 0.f};
        f16x8 pfh[2][2];   // prefetched h0 frags, 2 slots in flight

        auto loadslot = [&](int s, int buf) {   // sc1 (LLC) loads, L1/L2 bypass
            char* sb = ringG + (size_t)(s & smask) * 4096 + (size_t)lane * 16;
#pragma unroll
            for (int kf = 0; kf < 2; ++kf) {
                union { u64 d[2]; f16x8 v; } Uh;
                u64* ph = (u64*)(sb + kf * 1024);
                Uh.d[0] = __hip_atomic_load(ph,     __ATOMIC_RELAXED, __HIP_MEMORY_SCOPE_AGENT);
                Uh.d[1] = __hip_atomic_load(ph + 1, __ATOMIC_RELAXED, __HIP_MEMORY_SCOPE_AGENT);
                pfh[buf][kf] = Uh.v;
            }
        };
        u64 pfcache = 0;
        __syncthreads();

#pragma unroll 1
        for (int cs = 0; cs < T; cs += CHUNK) {
            // need chunk (cs/8 + 1) fully acked (prefetch reaches cs+9):
            // flag >= cs+16 in sum-counter units (8 waves x chunks).
            u64 need = (u64)((cs + 16 > T) ? T : cs + 16);
            if (tid == 0 && pfcache < need) pfcache = pollflag(prodF, need);
            BAR_LGKM();                                        // release all waves
            if (cs == 0) { loadslot(0, 0); loadslot(1, 1); }
#pragma unroll
            for (int cc = 0; cc < CHUNK; ++cc) {
                const int s = cs + cc;
                const int buf = s & 1, par = s & 1;
                f16x8 ch0 = *(const f16x8*)&bBuf[par][0][lane][0];
                f16x8 ch1 = *(const f16x8*)&bBuf[par][1][lane][0];
                float hq[2];
#pragma unroll
                for (int u = 0; u < 2; ++u) {
                    // two parallel 2-deep chains: pf-side (regs, starts
                    // immediately) and ch-side (after ds_read lands).
                    f32x4 GA = MFMA(Ahi[u * 4 + 0], pfh[buf][0], bias[u]);
                    GA = MFMA(Ahi[u * 4 + 1], pfh[buf][1], GA);
                    f32x4 GB = MFMA(Ahi[u * 4 + 2], ch0, z4);
                    GB = MFMA(Ahi[u * 4 + 3], ch1, GB);
                    lstm_act(GA[0] + GB[0], GA[1] + GB[1],
                             GA[2] + GB[2], GA[3] + GB[3], c[u], hq[u]);
                }
                // prefetch slot s+2 into the buf being retired this step;
                // stays in flight across the lgkm-only barrier.
                if (s + 2 < T) loadslot(s + 2, buf);
                u32 pH = packf16((f16)hq[0], (f16)hq[1]);
                *(u32*)&bBuf[par ^ 1][kfL][row][2 * q] = pH;
                if (s == T - 1) {
                    hf[n][(tt0 + 0) * 4 + q] = hq[0];
                    hf[n][(tt0 + 1) * 4 + q] = hq[1];
                }
                BAR_LGKM();
            }
            // chunk's ring reads were consumed (data-dep waits) before the
            // final per-step barrier; safe to signal with a relaxed store.
            if (tid == 0)
                __hip_atomic_store(consF, (u64)(cs + CHUNK),
                                   __ATOMIC_RELAXED, __HIP_MEMORY_SCOPE_AGENT);
        }

        // classifier: relu(h1 @ Wc1^T + bc1) @ Wc2^T + bc2
        __syncthreads();
        if (tid < GW * 32) {
            int nn = tid >> 5, m = tid & 31;
            float acc = bc1[m];
            const float* wr = Wc1 + m * HD;
#pragma unroll
            for (int k = 0; k < HD; ++k) acc += wr[k] * hf[nn][k];
            hid[nn][m] = fmaxf(acc, 0.0f);
        }
        __syncthreads();
        if (tid < GW) {
            float acc = bc2[0];
#pragma unroll
            for (int k = 0; k < HD / 2; ++k) acc += Wc2[k] * hid[tid][k];
            out[b0 + tid] = acc;
        }
    }
}

extern "C" void kernel_launch(void* const* d_in, const int* in_sizes, int n_in,
                              void* d_out, int out_size, void* d_ws, size_t ws_size,
                              hipStream_t stream) {
    const float* x    = (const float*)d_in[0];
    const float* Wih0 = (const float*)d_in[1];
    const float* Whh0 = (const float*)d_in[2];
    const float* bih0 = (const float*)d_in[3];
    const float* bhh0 = (const float*)d_in[4];
    const float* Wih1 = (const float*)d_in[5];
    const float* Whh1 = (const float*)d_in[6];
    const float* bih1 = (const float*)d_in[7];
    const float* bhh1 = (const float*)d_in[8];
    const float* Wc1  = (const float*)d_in[9];
    const float* bc1  = (const float*)d_in[10];
    const float* Wc2  = (const float*)d_in[11];
    const float* bc2  = (const float*)d_in[12];

    const int B = out_size;            // output [B,1]
    const int T = in_sizes[0] / B;     // x is [B,T,1]
    const int groups = B / GW;         // 128

    // ring depth from ws_size: 8 slots minimum; deeper if room
    int slots = 8;
    while (slots < 64 &&
           65536 + (size_t)groups * (size_t)(slots * 2) * 4096 <= ws_size)
        slots *= 2;

    hipLaunchKernelGGL(init_ws_k, dim3(32), dim3(256), 0, stream, (u64*)d_ws);
    hipLaunchKernelGGL(lstm2_pair, dim3(2 * groups), dim3(NT), 0, stream,
                       x, Wih0, Whh0, bih0, bhh0,
                       Wih1, Whh1, bih1, bhh1,
                       Wc1, bc1, Wc2, bc2,
                       (float*)d_out, (char*)d_ws, T, groups, slots);
}